// Round 6
// baseline (567.223 us; speedup 1.0000x reference)
//
#include <hip/hip_runtime.h>
#include <math.h>

#define DIMM 512
#define NB 8
#define QLEN 1024
#define KLEN 4096

typedef __attribute__((ext_vector_type(4))) float floatx4;
typedef __attribute__((ext_vector_type(8))) short short8;     // 8 bf16 (4 VGPRs) MFMA frag
typedef __attribute__((ext_vector_type(4))) unsigned short ushort4v;
typedef __attribute__((ext_vector_type(8))) unsigned short ushort8v;

// ---------- bf16 helpers (bit-level, RNE) ----------
static __device__ __forceinline__ unsigned short f2bf(float f) {
    unsigned u = __builtin_bit_cast(unsigned, f);
    u += 0x7FFFu + ((u >> 16) & 1u);
    return (unsigned short)(u >> 16);
}
static __device__ __forceinline__ float bf2f(unsigned short h) {
    unsigned u = ((unsigned)h) << 16;
    return __builtin_bit_cast(float, u);
}
// register-lean tanh via __expf
static __device__ __forceinline__ float fast_tanh(float x) {
    float e = __expf(-2.0f * fabsf(x));
    float t = (1.0f - e) / (1.0f + e);
    return copysignf(t, x);
}

// ---------- async global->LDS, 16B per lane ----------
static __device__ __forceinline__ void gload16(const unsigned short* g, unsigned short* l) {
    __builtin_amdgcn_global_load_lds(
        (__attribute__((address_space(1))) void*)const_cast<unsigned short*>(g),
        (__attribute__((address_space(3))) void*)l,
        16, 0, 0);
}

// ---------- prep: fp32 [R,512] -> bf16 [R,1024] = [lo | hi] ----------
__global__ __launch_bounds__(256) void split_k(const float* __restrict__ x,
                                               unsigned short* __restrict__ dst) {
    int idx = blockIdx.x * 256 + threadIdx.x;          // one float4 per thread
    float4 v = ((const float4*)x)[idx];
    int r = idx >> 7;                                  // 128 float4 per row (C=512)
    int c = (idx & 127) << 2;
    float f[4] = {v.x, v.y, v.z, v.w};
    ushort4v hi, lo;
#pragma unroll
    for (int e = 0; e < 4; ++e) {
        unsigned short h = f2bf(f[e]);
        hi[e] = h;
        lo[e] = f2bf(f[e] - bf2f(h));
    }
    unsigned short* row = dst + ((size_t)r << 10);     // row stride 1024
    *(ushort4v*)(row + c) = lo;
    *(ushort4v*)(row + 512 + c) = hi;
}

// ---------- prep: fp32 [R,C] -> bf16 at dst[r*ldd + off + c] ----------
__global__ __launch_bounds__(256) void conv_hi(const float* __restrict__ x,
                                               unsigned short* __restrict__ dst,
                                               int c4shift, int ldd, int off) {
    int idx = blockIdx.x * 256 + threadIdx.x;
    float4 v = ((const float4*)x)[idx];
    int r = idx >> c4shift;
    int c = (idx & ((1 << c4shift) - 1)) << 2;
    ushort4v hi;
    hi[0] = f2bf(v.x); hi[1] = f2bf(v.y); hi[2] = f2bf(v.z); hi[3] = f2bf(v.w);
    *(ushort4v*)(dst + (size_t)r * ldd + off + c) = hi;
}

// ---------- fused ctx prep: read ctx ONCE ->
//   hilo [b,4096, hi512|lo512] (QK B-operand) + ctxT [b,512,4096] bf16 hi (PV B) ----------
__global__ __launch_bounds__(256) void prep_ctx(const float* __restrict__ ctx,
                                                unsigned short* __restrict__ hilo,
                                                unsigned short* __restrict__ ctxT) {
    __shared__ unsigned short tile[64][66];            // +2 pad: spread banks
    int b = blockIdx.z;
    int c0 = blockIdx.x * 64;                          // dim index
    int k0 = blockIdx.y * 64;                          // seq index
    const float* src = ctx + ((size_t)b * KLEN + k0) * DIMM + c0;
    unsigned short* hl = hilo + ((size_t)b * KLEN + k0) * 1024 + c0;
    int t = threadIdx.x;
    int rr = t >> 4, cc4 = (t & 15) * 4;
#pragma unroll
    for (int it = 0; it < 4; ++it) {
        int r = rr + it * 16;
        float4 v = *(const float4*)(src + (size_t)r * DIMM + cc4);
        float f[4] = {v.x, v.y, v.z, v.w};
        ushort4v hi, lo;
#pragma unroll
        for (int e = 0; e < 4; ++e) {
            unsigned short h = f2bf(f[e]);
            hi[e] = h;
            lo[e] = f2bf(f[e] - bf2f(h));
            tile[r][cc4 + e] = h;
        }
        *(ushort4v*)(hl + (size_t)r * 1024 + cc4) = hi;
        *(ushort4v*)(hl + (size_t)r * 1024 + 512 + cc4) = lo;
    }
    __syncthreads();
#pragma unroll
    for (int it = 0; it < 2; ++it) {
        int u = t + it * 256;
        int c = u >> 3;                                // 0..63 (dim within tile)
        int kk = (u & 7) * 8;                          // 16B chunk along k
        ushort8v o;
#pragma unroll
        for (int e = 0; e < 8; ++e) o[e] = tile[kk + e][c];
        *(ushort8v*)(ctxT + ((size_t)b * DIMM + c0 + c) * KLEN + k0 + kk) = o;
    }
}

// ---------- softmax over rows of 4096: fp32 in-place + bf16 copy ----------
__global__ __launch_bounds__(256) void softmax_k(float* __restrict__ S,
                                                 unsigned short* __restrict__ Pb) {
    size_t row = blockIdx.x;
    float* p = S + row * KLEN;
    int t = threadIdx.x;
    int lane = t & 63, wv = t >> 6;
    float4 v[4];
    float mx = -3.0e38f;
#pragma unroll
    for (int i = 0; i < 4; ++i) {
        v[i] = *(const float4*)(p + i * 1024 + t * 4);
        mx = fmaxf(mx, fmaxf(fmaxf(v[i].x, v[i].y), fmaxf(v[i].z, v[i].w)));
    }
#pragma unroll
    for (int m = 32; m >= 1; m >>= 1) mx = fmaxf(mx, __shfl_xor(mx, m, 64));
    __shared__ float redm[4], reds[4];
    if (lane == 0) redm[wv] = mx;
    __syncthreads();
    mx = fmaxf(fmaxf(redm[0], redm[1]), fmaxf(redm[2], redm[3]));
    float sum = 0.f;
#pragma unroll
    for (int i = 0; i < 4; ++i) {
        v[i].x = __expf(v[i].x - mx); v[i].y = __expf(v[i].y - mx);
        v[i].z = __expf(v[i].z - mx); v[i].w = __expf(v[i].w - mx);
        sum += v[i].x + v[i].y + v[i].z + v[i].w;
    }
#pragma unroll
    for (int m = 32; m >= 1; m >>= 1) sum += __shfl_xor(sum, m, 64);
    if (lane == 0) reds[wv] = sum;
    __syncthreads();
    float inv = 1.0f / (reds[0] + reds[1] + reds[2] + reds[3]);
    unsigned short* pb = Pb + row * KLEN;
#pragma unroll
    for (int i = 0; i < 4; ++i) {
        float4 w;
        w.x = v[i].x * inv; w.y = v[i].y * inv; w.z = v[i].z * inv; w.w = v[i].w * inv;
        *(float4*)(p + i * 1024 + t * 4) = w;
        ushort4v h;
        h[0] = f2bf(w.x); h[1] = f2bf(w.y); h[2] = f2bf(w.z); h[3] = f2bf(w.w);
        *(ushort4v*)(pb + i * 1024 + t * 4) = h;
    }
}

// ---------- generic C = A * B^T GEMM (both operands K-major bf16), fp32 acc ----------
// BM=128 x BN tile, BK=64, 4 waves 2x2; wave = 4 x (BN/32) frags of 16x16x32 MFMA.
// R6 theory: the 2-barrier loop is LDS-READ-BW-bound, not barrier-bound. Per K-tile
//   per CU (4 blk x 4 waves): 256 ds_read_b128 ~ 2-3k cy on the shared LDS port vs
//   ~620 cy/SIMD of MFMA -> MfmaUtil ~43%, conflicts 0, HBM 33% all consistent.
//   That's why dbuf (r2) and 8-phase graft (r4) were null: they attack barriers.
// ADIR (new, QK only): A-fragments read DIRECTLY from global (A is 16 MiB,
//   L3-resident; wn-pair re-reads hit L1). Halves LDS traffic, halves staging
//   loads, frees sA (LDS 48->16 KB). Frag mapping derived from the XOR swizzle:
//   af[i] = A[row, ka + (s*4+quad)*8] -- BIT-IDENTICAL MFMA inputs vs the LDS
//   path (swizzle cancels: chunk^(mlane&7)^(mlane&7)), so absmax must not move.
// SWZ: z-chunked bijective remap for PV/out (A-panel sharers -> one XCD; r3 +6us).
// QK keeps default mapping (id%8=bx%8 co-locates the 64 MiB B operand; r1 measured
//   breaking it = +80 MB fetch).
// EPI: 0 = store fp32; 1 = store bf16; 2 = tanh(x + bias[col]) fp32
// REMAP (QK split-bf16, virtual K=1536): A=[Al|Ah], B=[Bh|Bl], 3 panels.
template <int EPI, bool REMAP, int BN, bool SWZ, bool ADIR>
__global__ __launch_bounds__(256, 4) void gemm_bt(
    const unsigned short* __restrict__ A,
    const unsigned short* __restrict__ Bm,
    float* __restrict__ Cf, unsigned short* __restrict__ Cb,
    const float* __restrict__ bias,
    int Ktiles, long lda, long ldb, long ldc,
    long a_bs, long b_bs, long c_bs) {
    constexpr int NF = BN / 32;                        // B frags per wave (4 or 2)
    __shared__ unsigned short sA[ADIR ? 64 : 128 * 64];
    __shared__ unsigned short sB[BN * 64];

    int bx, by, bz;
    if constexpr (SWZ) {
        int nx = gridDim.x, ny = gridDim.y;
        int nblk = nx * ny * (int)gridDim.z;
        int id = (int)blockIdx.x + nx * ((int)blockIdx.y + ny * (int)blockIdx.z);
        int wid = (id & 7) * (nblk >> 3) + (id >> 3);
        bx = wid % nx;
        int rem = wid / nx;
        by = rem % ny;
        bz = rem / ny;
    } else {
        bx = blockIdx.x; by = blockIdx.y; bz = blockIdx.z;
    }

    const int tid = threadIdx.x;
    const int lane = tid & 63;
    const int wv = tid >> 6;
    const int wm = wv >> 1, wn = wv & 1;
    const int mlane = lane & 15, quad = lane >> 4;
    const unsigned short* Ab = A + (size_t)bz * a_bs + (size_t)by * 128 * lda;
    const unsigned short* Bb = Bm + (size_t)bz * b_bs + (size_t)bx * BN * ldb;
    const int r8 = tid >> 3;
    const int c8 = (tid & 7) << 3;
    const int cg = ((tid & 7) ^ ((tid >> 3) & 7)) << 3;
    unsigned short* la = sA + r8 * 64 + c8;            // unused when ADIR
    unsigned short* lb = sB + r8 * 64 + c8;

    // per-lane A-fragment row bases (ADIR): row = by*128 + wm*64 + i*16 + mlane
    const unsigned short* aRow[4];
    if constexpr (ADIR) {
#pragma unroll
        for (int i = 0; i < 4; ++i)
            aRow[i] = Ab + (size_t)(wm * 64 + i * 16 + mlane) * lda + quad * 8;
    }

    floatx4 acc[4][NF] = {};

    for (int kt = 0; kt < Ktiles; ++kt) {
        long kv = (long)kt * 64;
        long ka = kv, kb = kv;
        if (REMAP) {
            ka = kv < 512 ? kv + 512 : (kv < 1024 ? kv : kv - 1024);
            kb = kv < 1024 ? kv : kv - 1024;
        }
        if (kt) __syncthreads();                       // protect sB (and sA) overwrite
        const unsigned short* gb = Bb + (size_t)r8 * ldb + kb + cg;
        if constexpr (!ADIR) {
            const unsigned short* ga = Ab + (size_t)r8 * lda + ka + cg;
#pragma unroll
            for (int it = 0; it < 4; ++it)
                gload16(ga + (size_t)(it * 32) * lda, la + it * 2048);
        }
#pragma unroll
        for (int it = 0; it < BN / 32; ++it)
            gload16(gb + (size_t)(it * 32) * ldb, lb + it * 2048);
        __syncthreads();                               // drains vmcnt before barrier
#pragma unroll
        for (int s = 0; s < 2; ++s) {
            const int swz = (((s * 4 + quad) ^ (mlane & 7)) << 3);
            short8 af[4];
#pragma unroll
            for (int i = 0; i < 4; ++i) {
                if constexpr (ADIR)
                    af[i] = *(const short8*)(aRow[i] + ka + s * 32);
                else
                    af[i] = *(const short8*)(sA + (wm * 64 + i * 16 + mlane) * 64 + swz);
            }
#pragma unroll
            for (int j = 0; j < NF; ++j) {
                short8 bfj = *(const short8*)(sB + (wn * (BN / 2) + j * 16 + mlane) * 64 + swz);
#pragma unroll
                for (int i = 0; i < 4; ++i)
                    acc[i][j] = __builtin_amdgcn_mfma_f32_16x16x32_bf16(af[i], bfj, acc[i][j], 0, 0, 0);
            }
        }
    }

    size_t crow0 = (size_t)by * 128 + wm * 64 + quad * 4;
    size_t ccol0 = (size_t)bx * BN + wn * (BN / 2) + mlane;
    size_t cbase = (size_t)bz * c_bs;
#pragma unroll
    for (int i = 0; i < 4; ++i) {
#pragma unroll
        for (int j = 0; j < NF; ++j) {
            size_t gr = crow0 + i * 16;
            size_t gc = ccol0 + j * 16;
#pragma unroll
            for (int r = 0; r < 4; ++r) {
                float vv = acc[i][j][r];
                size_t off = cbase + (gr + r) * ldc + gc;
                if (EPI == 0) Cf[off] = vv;
                else if (EPI == 1) Cb[off] = f2bf(vv);
                else Cf[off] = fast_tanh(vv + bias[gc]);
            }
        }
    }
}

extern "C" void kernel_launch(void* const* d_in, const int* in_sizes, int n_in,
                              void* d_out, int out_size, void* d_ws, size_t ws_size,
                              hipStream_t stream) {
    (void)in_sizes; (void)n_in; (void)out_size; (void)ws_size;
    const float* outp = (const float*)d_in[0];   // [8,1024,512]
    const float* ctx  = (const float*)d_in[1];   // [8,4096,512]
    const float* W    = (const float*)d_in[2];   // [512,1024]  (already K-major for C=A*W^T)
    const float* bias = (const float*)d_in[3];   // [512]

    float* out0 = (float*)d_out;                              // [8,1024,512]
    float* attn = out0 + (size_t)NB * QLEN * DIMM;            // [8,1024,4096]

    unsigned char* w = (unsigned char*)d_ws;
    // Region plan (113 MiB peak, time-aliased):
    //   R1 (16 MiB): A2 = [outLo|outHi]          -> later: combined [mix | outHi]
    //   R2 (64 MiB): B2 = [ctxHi|ctxLo]          -> later: attn bf16
    //   R3 (32 MiB): ctxT hi bf16 [b,512,4096]
    //   R4 ( 1 MiB): W bf16
    unsigned short* R1 = (unsigned short*)(w);
    unsigned short* R2 = (unsigned short*)(w + (16ull << 20));
    unsigned short* R3 = (unsigned short*)(w + (80ull << 20));
    unsigned short* R4 = (unsigned short*)(w + (112ull << 20));

    // 1. prep (ctx read once: hilo + transpose fused)
    split_k<<<4096, 256, 0, stream>>>(outp, R1);                     // output -> [lo|hi]
    prep_ctx<<<dim3(8, 64, 8), 256, 0, stream>>>(ctx, R2, R3);       // ctx -> B2 + ctxT
    conv_hi<<<512, 256, 0, stream>>>(W, R4, 8, 1024, 0);             // W -> bf16

    // 2. QK^T split-bf16 (virtual K=1536), A-direct-from-global inner loop.
    //    Split into 2 dispatches (batches 0-3 / 4-7): same 4 blk/CU occupancy and
    //    same B-panel XCD locality, but halves QK's top-5 footprint so the hidden
    //    kernels (PV/softmax/prep) finally surface in the profile.
    for (int h = 0; h < 2; ++h) {
        gemm_bt<0, true, 128, false, true><<<dim3(32, 8, 4), 256, 0, stream>>>(
            R1 + (size_t)h * 4 * QLEN * 1024,
            R2 + (size_t)h * 4 * KLEN * 1024,
            attn + (size_t)h * 4 * QLEN * KLEN, nullptr, nullptr,
            24, 1024, 1024, 4096,
            (long)QLEN * 1024, (long)KLEN * 1024, (long)QLEN * KLEN);
    }

    // 3. softmax rows: fp32 in-place + bf16 copy into R2 (B2 is dead)
    softmax_k<<<8192, 256, 0, stream>>>(attn, R2);

    // 4. PV: mix = attn_bf16 * ctxT^T -> combined[:,0:512] (bf16, overwrites dead outLo)
    gemm_bt<1, false, 64, true, false><<<dim3(8, 8, 8), 256, 0, stream>>>(
        R2, R3, nullptr, R1, nullptr,
        64, 4096, 4096, 1024,
        (long)QLEN * KLEN, (long)DIMM * KLEN, (long)QLEN * 1024);

    // 5. out = tanh(combined * W^T + b)   (combined = [mix | outHi] already assembled)
    gemm_bt<2, false, 64, true, false><<<dim3(8, 64, 1), 256, 0, stream>>>(
        R1, R4, out0, nullptr, bias,
        16, 1024, 1024, 512, 0, 0, 0);
}

// Round 7
// 459.752 us; speedup vs baseline: 1.2338x; 1.2338x over previous
//
#include <hip/hip_runtime.h>
#include <math.h>

#define DIMM 512
#define NB 8
#define QLEN 1024
#define KLEN 4096

typedef __attribute__((ext_vector_type(4))) float floatx4;
typedef __attribute__((ext_vector_type(8))) short short8;     // 8 bf16 (4 VGPRs) MFMA frag
typedef __attribute__((ext_vector_type(4))) unsigned short ushort4v;
typedef __attribute__((ext_vector_type(8))) unsigned short ushort8v;

// ---------- bf16 helpers (bit-level, RNE) ----------
static __device__ __forceinline__ unsigned short f2bf(float f) {
    unsigned u = __builtin_bit_cast(unsigned, f);
    u += 0x7FFFu + ((u >> 16) & 1u);
    return (unsigned short)(u >> 16);
}
static __device__ __forceinline__ float bf2f(unsigned short h) {
    unsigned u = ((unsigned)h) << 16;
    return __builtin_bit_cast(float, u);
}
// register-lean tanh via __expf
static __device__ __forceinline__ float fast_tanh(float x) {
    float e = __expf(-2.0f * fabsf(x));
    float t = (1.0f - e) / (1.0f + e);
    return copysignf(t, x);
}

// ---------- async global->LDS, 16B per lane ----------
static __device__ __forceinline__ void gload16(const unsigned short* g, unsigned short* l) {
    __builtin_amdgcn_global_load_lds(
        (__attribute__((address_space(1))) void*)const_cast<unsigned short*>(g),
        (__attribute__((address_space(3))) void*)l,
        16, 0, 0);
}

// ---------- prep: fp32 [R,512] -> bf16 [R,1024] = [lo | hi] ----------
__global__ __launch_bounds__(256) void split_k(const float* __restrict__ x,
                                               unsigned short* __restrict__ dst) {
    int idx = blockIdx.x * 256 + threadIdx.x;          // one float4 per thread
    float4 v = ((const float4*)x)[idx];
    int r = idx >> 7;                                  // 128 float4 per row (C=512)
    int c = (idx & 127) << 2;
    float f[4] = {v.x, v.y, v.z, v.w};
    ushort4v hi, lo;
#pragma unroll
    for (int e = 0; e < 4; ++e) {
        unsigned short h = f2bf(f[e]);
        hi[e] = h;
        lo[e] = f2bf(f[e] - bf2f(h));
    }
    unsigned short* row = dst + ((size_t)r << 10);     // row stride 1024
    *(ushort4v*)(row + c) = lo;
    *(ushort4v*)(row + 512 + c) = hi;
}

// ---------- prep: fp32 [R,C] -> bf16 at dst[r*ldd + off + c] ----------
__global__ __launch_bounds__(256) void conv_hi(const float* __restrict__ x,
                                               unsigned short* __restrict__ dst,
                                               int c4shift, int ldd, int off) {
    int idx = blockIdx.x * 256 + threadIdx.x;
    float4 v = ((const float4*)x)[idx];
    int r = idx >> c4shift;
    int c = (idx & ((1 << c4shift) - 1)) << 2;
    ushort4v hi;
    hi[0] = f2bf(v.x); hi[1] = f2bf(v.y); hi[2] = f2bf(v.z); hi[3] = f2bf(v.w);
    *(ushort4v*)(dst + (size_t)r * ldd + off + c) = hi;
}

// ---------- fused ctx prep: read ctx ONCE ->
//   hilo [b,4096, hi512|lo512] (QK B-operand) + ctxT [b,512,4096] bf16 hi (PV B) ----------
__global__ __launch_bounds__(256) void prep_ctx(const float* __restrict__ ctx,
                                                unsigned short* __restrict__ hilo,
                                                unsigned short* __restrict__ ctxT) {
    __shared__ unsigned short tile[64][66];            // +2 pad: spread banks
    int b = blockIdx.z;
    int c0 = blockIdx.x * 64;                          // dim index
    int k0 = blockIdx.y * 64;                          // seq index
    const float* src = ctx + ((size_t)b * KLEN + k0) * DIMM + c0;
    unsigned short* hl = hilo + ((size_t)b * KLEN + k0) * 1024 + c0;
    int t = threadIdx.x;
    int rr = t >> 4, cc4 = (t & 15) * 4;
#pragma unroll
    for (int it = 0; it < 4; ++it) {
        int r = rr + it * 16;
        float4 v = *(const float4*)(src + (size_t)r * DIMM + cc4);
        float f[4] = {v.x, v.y, v.z, v.w};
        ushort4v hi, lo;
#pragma unroll
        for (int e = 0; e < 4; ++e) {
            unsigned short h = f2bf(f[e]);
            hi[e] = h;
            lo[e] = f2bf(f[e] - bf2f(h));
            tile[r][cc4 + e] = h;
        }
        *(ushort4v*)(hl + (size_t)r * 1024 + cc4) = hi;
        *(ushort4v*)(hl + (size_t)r * 1024 + 512 + cc4) = lo;
    }
    __syncthreads();
#pragma unroll
    for (int it = 0; it < 2; ++it) {
        int u = t + it * 256;
        int c = u >> 3;                                // 0..63 (dim within tile)
        int kk = (u & 7) * 8;                          // 16B chunk along k
        ushort8v o;
#pragma unroll
        for (int e = 0; e < 8; ++e) o[e] = tile[kk + e][c];
        *(ushort8v*)(ctxT + ((size_t)b * DIMM + c0 + c) * KLEN + k0 + kk) = o;
    }
}

// ---------- softmax over rows of 4096: fp32 in-place + bf16 copy ----------
__global__ __launch_bounds__(256) void softmax_k(float* __restrict__ S,
                                                 unsigned short* __restrict__ Pb) {
    size_t row = blockIdx.x;
    float* p = S + row * KLEN;
    int t = threadIdx.x;
    int lane = t & 63, wv = t >> 6;
    float4 v[4];
    float mx = -3.0e38f;
#pragma unroll
    for (int i = 0; i < 4; ++i) {
        v[i] = *(const float4*)(p + i * 1024 + t * 4);
        mx = fmaxf(mx, fmaxf(fmaxf(v[i].x, v[i].y), fmaxf(v[i].z, v[i].w)));
    }
#pragma unroll
    for (int m = 32; m >= 1; m >>= 1) mx = fmaxf(mx, __shfl_xor(mx, m, 64));
    __shared__ float redm[4], reds[4];
    if (lane == 0) redm[wv] = mx;
    __syncthreads();
    mx = fmaxf(fmaxf(redm[0], redm[1]), fmaxf(redm[2], redm[3]));
    float sum = 0.f;
#pragma unroll
    for (int i = 0; i < 4; ++i) {
        v[i].x = __expf(v[i].x - mx); v[i].y = __expf(v[i].y - mx);
        v[i].z = __expf(v[i].z - mx); v[i].w = __expf(v[i].w - mx);
        sum += v[i].x + v[i].y + v[i].z + v[i].w;
    }
#pragma unroll
    for (int m = 32; m >= 1; m >>= 1) sum += __shfl_xor(sum, m, 64);
    if (lane == 0) reds[wv] = sum;
    __syncthreads();
    float inv = 1.0f / (reds[0] + reds[1] + reds[2] + reds[3]);
    unsigned short* pb = Pb + row * KLEN;
#pragma unroll
    for (int i = 0; i < 4; ++i) {
        float4 w;
        w.x = v[i].x * inv; w.y = v[i].y * inv; w.z = v[i].z * inv; w.w = v[i].w * inv;
        *(float4*)(p + i * 1024 + t * 4) = w;
        ushort4v h;
        h[0] = f2bf(w.x); h[1] = f2bf(w.y); h[2] = f2bf(w.z); h[3] = f2bf(w.w);
        *(ushort4v*)(pb + i * 1024 + t * 4) = h;
    }
}

// ---------- generic C = A * B^T GEMM (both operands K-major bf16), fp32 acc ----------
// BM=128 x BN tile, BK=64, 4 waves 2x2; wave = 4 x (BN/32) frags of 16x16x32 MFMA.
// R7: full revert to the r3 structure (session best, 463.7 us). QK structure is
//   FROZEN: 4 experiments (r1 xcd-chunk, r2 counted-vmcnt dbuf, r4 8-phase,
//   r6 A-direct) all regressed; 107 us / 963 TF is its plateau. r6's collapse
//   (MfmaUtil 17.7, VALUBusy 7.2) proved the loop is NOT LDS-BW-bound: per-lane
//   global frag loads went latency-bound, i.e. the LDS reads were being hidden
//   by 4-blk/CU wave overlap all along.
// VISIBILITY: QK launched as 2 z-split dispatches (batches 0-3 / 4-7, ~55 us
//   each) purely so PV/softmax/prep_ctx finally surface in the top-5 profile.
// SWZ (PV/out only): z-chunked bijective remap -> XCD n owns batch n; A-panel
//   sharers co-resident (r3 measured +6 us). QK keeps default mapping
//   (id%8=bx%8 already co-locates the 64 MiB B operand's sharers; r1 measured
//   breaking it = +80 MB fetch, +12 us).
// EPI: 0 = store fp32; 1 = store bf16; 2 = tanh(x + bias[col]) fp32
// REMAP (QK split-bf16, virtual K=1536): A=[Al|Ah], B=[Bh|Bl], 3 panels.
template <int EPI, bool REMAP, int BN, bool SWZ>
__global__ __launch_bounds__(256, 4) void gemm_bt(
    const unsigned short* __restrict__ A,
    const unsigned short* __restrict__ Bm,
    float* __restrict__ Cf, unsigned short* __restrict__ Cb,
    const float* __restrict__ bias,
    int Ktiles, long lda, long ldb, long ldc,
    long a_bs, long b_bs, long c_bs) {
    constexpr int NF = BN / 32;                        // B frags per wave (4 or 2)
    __shared__ unsigned short sA[128 * 64];
    __shared__ unsigned short sB[BN * 64];

    int bx, by, bz;
    if constexpr (SWZ) {
        int nx = gridDim.x, ny = gridDim.y;
        int nblk = nx * ny * (int)gridDim.z;
        int id = (int)blockIdx.x + nx * ((int)blockIdx.y + ny * (int)blockIdx.z);
        int wid = (id & 7) * (nblk >> 3) + (id >> 3);
        bx = wid % nx;
        int rem = wid / nx;
        by = rem % ny;
        bz = rem / ny;
    } else {
        bx = blockIdx.x; by = blockIdx.y; bz = blockIdx.z;
    }

    const int tid = threadIdx.x;
    const int lane = tid & 63;
    const int wv = tid >> 6;
    const int wm = wv >> 1, wn = wv & 1;
    const int mlane = lane & 15, quad = lane >> 4;
    const unsigned short* Ab = A + (size_t)bz * a_bs + (size_t)by * 128 * lda;
    const unsigned short* Bb = Bm + (size_t)bz * b_bs + (size_t)bx * BN * ldb;
    const int r8 = tid >> 3;
    const int c8 = (tid & 7) << 3;
    const int cg = ((tid & 7) ^ ((tid >> 3) & 7)) << 3;
    unsigned short* la = sA + r8 * 64 + c8;
    unsigned short* lb = sB + r8 * 64 + c8;

    floatx4 acc[4][NF] = {};

    for (int kt = 0; kt < Ktiles; ++kt) {
        long kv = (long)kt * 64;
        long ka = kv, kb = kv;
        if (REMAP) {
            ka = kv < 512 ? kv + 512 : (kv < 1024 ? kv : kv - 1024);
            kb = kv < 1024 ? kv : kv - 1024;
        }
        if (kt) __syncthreads();                       // protect LDS from overwrite
        const unsigned short* ga = Ab + (size_t)r8 * lda + ka + cg;
        const unsigned short* gb = Bb + (size_t)r8 * ldb + kb + cg;
#pragma unroll
        for (int it = 0; it < 4; ++it)
            gload16(ga + (size_t)(it * 32) * lda, la + it * 2048);
#pragma unroll
        for (int it = 0; it < BN / 32; ++it)
            gload16(gb + (size_t)(it * 32) * ldb, lb + it * 2048);
        __syncthreads();                               // drains vmcnt before barrier
#pragma unroll
        for (int s = 0; s < 2; ++s) {
            const int swz = (((s * 4 + quad) ^ (mlane & 7)) << 3);
            short8 af[4];
#pragma unroll
            for (int i = 0; i < 4; ++i)
                af[i] = *(const short8*)(sA + (wm * 64 + i * 16 + mlane) * 64 + swz);
#pragma unroll
            for (int j = 0; j < NF; ++j) {             // stream bf: keeps live regs low
                short8 bfj = *(const short8*)(sB + (wn * (BN / 2) + j * 16 + mlane) * 64 + swz);
#pragma unroll
                for (int i = 0; i < 4; ++i)
                    acc[i][j] = __builtin_amdgcn_mfma_f32_16x16x32_bf16(af[i], bfj, acc[i][j], 0, 0, 0);
            }
        }
    }

    // epilogue: C/D layout col=lane&15, row=quad*4+reg
    size_t crow0 = (size_t)by * 128 + wm * 64 + quad * 4;
    size_t ccol0 = (size_t)bx * BN + wn * (BN / 2) + mlane;
    size_t cbase = (size_t)bz * c_bs;
#pragma unroll
    for (int i = 0; i < 4; ++i) {
#pragma unroll
        for (int j = 0; j < NF; ++j) {
            size_t gr = crow0 + i * 16;
            size_t gc = ccol0 + j * 16;
#pragma unroll
            for (int r = 0; r < 4; ++r) {
                float vv = acc[i][j][r];
                size_t off = cbase + (gr + r) * ldc + gc;
                if (EPI == 0) Cf[off] = vv;
                else if (EPI == 1) Cb[off] = f2bf(vv);
                else Cf[off] = fast_tanh(vv + bias[gc]);
            }
        }
    }
}

extern "C" void kernel_launch(void* const* d_in, const int* in_sizes, int n_in,
                              void* d_out, int out_size, void* d_ws, size_t ws_size,
                              hipStream_t stream) {
    (void)in_sizes; (void)n_in; (void)out_size; (void)ws_size;
    const float* outp = (const float*)d_in[0];   // [8,1024,512]
    const float* ctx  = (const float*)d_in[1];   // [8,4096,512]
    const float* W    = (const float*)d_in[2];   // [512,1024]  (already K-major for C=A*W^T)
    const float* bias = (const float*)d_in[3];   // [512]

    float* out0 = (float*)d_out;                              // [8,1024,512]
    float* attn = out0 + (size_t)NB * QLEN * DIMM;            // [8,1024,4096]

    unsigned char* w = (unsigned char*)d_ws;
    // Region plan (113 MiB peak, time-aliased):
    //   R1 (16 MiB): A2 = [outLo|outHi]          -> later: combined [mix | outHi]
    //   R2 (64 MiB): B2 = [ctxHi|ctxLo]          -> later: attn bf16
    //   R3 (32 MiB): ctxT hi bf16 [b,512,4096]
    //   R4 ( 1 MiB): W bf16
    unsigned short* R1 = (unsigned short*)(w);
    unsigned short* R2 = (unsigned short*)(w + (16ull << 20));
    unsigned short* R3 = (unsigned short*)(w + (80ull << 20));
    unsigned short* R4 = (unsigned short*)(w + (112ull << 20));

    // 1. prep (ctx read once: hilo + transpose fused)
    split_k<<<4096, 256, 0, stream>>>(outp, R1);                     // output -> [lo|hi]
    prep_ctx<<<dim3(8, 64, 8), 256, 0, stream>>>(ctx, R2, R3);       // ctx -> B2 + ctxT
    conv_hi<<<512, 256, 0, stream>>>(W, R4, 8, 1024, 0);             // W -> bf16

    // 2. QK^T split-bf16 (virtual K=1536) -> raw logits (proven 2-barrier kernel).
    //    2 z-split dispatches (batches 0-3 / 4-7): identical per-block work &
    //    locality, ~55 us each -> hidden kernels surface in top-5 next profile.
    for (int h = 0; h < 2; ++h) {
        gemm_bt<0, true, 128, false><<<dim3(32, 8, 4), 256, 0, stream>>>(
            R1 + (size_t)h * 4 * QLEN * 1024,
            R2 + (size_t)h * 4 * KLEN * 1024,
            attn + (size_t)h * 4 * QLEN * KLEN, nullptr, nullptr,
            24, 1024, 1024, 4096,
            (long)QLEN * 1024, (long)KLEN * 1024, (long)QLEN * KLEN);
    }

    // 3. softmax rows: fp32 in-place + bf16 copy into R2 (B2 is dead)
    softmax_k<<<8192, 256, 0, stream>>>(attn, R2);

    // 4. PV: mix = attn_bf16 * ctxT^T -> combined[:,0:512] (bf16, overwrites dead outLo)
    gemm_bt<1, false, 64, true><<<dim3(8, 8, 8), 256, 0, stream>>>(
        R2, R3, nullptr, R1, nullptr,
        64, 4096, 4096, 1024,
        (long)QLEN * KLEN, (long)DIMM * KLEN, (long)QLEN * 1024);

    // 5. out = tanh(combined * W^T + b)   (combined = [mix | outHi] already assembled)
    gemm_bt<2, false, 64, true><<<dim3(8, 64, 1), 256, 0, stream>>>(
        R1, R4, out0, nullptr, bias,
        16, 1024, 1024, 512, 0, 0, 0);
}

// Round 8
// 455.151 us; speedup vs baseline: 1.2462x; 1.0101x over previous
//
#include <hip/hip_runtime.h>
#include <math.h>

#define DIMM 512
#define NB 8
#define QLEN 1024
#define KLEN 4096

typedef __attribute__((ext_vector_type(4))) float floatx4;
typedef __attribute__((ext_vector_type(8))) short short8;     // 8 bf16 (4 VGPRs) MFMA frag
typedef __attribute__((ext_vector_type(4))) unsigned short ushort4v;
typedef __attribute__((ext_vector_type(8))) unsigned short ushort8v;

// ---------- bf16 helpers (bit-level, RNE) ----------
static __device__ __forceinline__ unsigned short f2bf(float f) {
    unsigned u = __builtin_bit_cast(unsigned, f);
    u += 0x7FFFu + ((u >> 16) & 1u);
    return (unsigned short)(u >> 16);
}
static __device__ __forceinline__ float bf2f(unsigned short h) {
    unsigned u = ((unsigned)h) << 16;
    return __builtin_bit_cast(float, u);
}
// register-lean tanh via __expf
static __device__ __forceinline__ float fast_tanh(float x) {
    float e = __expf(-2.0f * fabsf(x));
    float t = (1.0f - e) / (1.0f + e);
    return copysignf(t, x);
}

// ---------- async global->LDS, 16B per lane ----------
static __device__ __forceinline__ void gload16(const unsigned short* g, unsigned short* l) {
    __builtin_amdgcn_global_load_lds(
        (__attribute__((address_space(1))) void*)const_cast<unsigned short*>(g),
        (__attribute__((address_space(3))) void*)l,
        16, 0, 0);
}

// ---------- fused prep: output fp32 [8192,512] -> [lo|hi] bf16 [8192,1024]
//            + W fp32 [512,1024] -> bf16 (blocks 4096..4607) ----------
__global__ __launch_bounds__(256) void prep_qw(const float* __restrict__ x,
                                               const float* __restrict__ Wf,
                                               unsigned short* __restrict__ dst,
                                               unsigned short* __restrict__ dstW) {
    int b = blockIdx.x;
    if (b < 4096) {
        int idx = b * 256 + threadIdx.x;               // one float4 per thread
        float4 v = ((const float4*)x)[idx];
        int r = idx >> 7;                              // 128 float4 per row (C=512)
        int c = (idx & 127) << 2;
        float f[4] = {v.x, v.y, v.z, v.w};
        ushort4v hi, lo;
#pragma unroll
        for (int e = 0; e < 4; ++e) {
            unsigned short h = f2bf(f[e]);
            hi[e] = h;
            lo[e] = f2bf(f[e] - bf2f(h));
        }
        unsigned short* row = dst + ((size_t)r << 10); // row stride 1024
        *(ushort4v*)(row + c) = lo;
        *(ushort4v*)(row + 512 + c) = hi;
    } else {
        int idx = (b - 4096) * 256 + threadIdx.x;      // W: 512x1024 fp32 = 131072 float4
        float4 v = ((const float4*)Wf)[idx];
        int r = idx >> 8;                              // 256 float4 per row (C=1024)
        int c = (idx & 255) << 2;
        ushort4v hi;
        hi[0] = f2bf(v.x); hi[1] = f2bf(v.y); hi[2] = f2bf(v.z); hi[3] = f2bf(v.w);
        *(ushort4v*)(dstW + (size_t)r * 1024 + c) = hi;
    }
}

// ---------- fused ctx prep: read ctx ONCE ->
//   hilo [b,4096, hi512|lo512] (QK B-operand) + ctxT [b,512,4096] bf16 hi (PV B) ----------
__global__ __launch_bounds__(256) void prep_ctx(const float* __restrict__ ctx,
                                                unsigned short* __restrict__ hilo,
                                                unsigned short* __restrict__ ctxT) {
    __shared__ unsigned short tile[64][66];            // +2 pad: spread banks
    int b = blockIdx.z;
    int c0 = blockIdx.x * 64;                          // dim index
    int k0 = blockIdx.y * 64;                          // seq index
    const float* src = ctx + ((size_t)b * KLEN + k0) * DIMM + c0;
    unsigned short* hl = hilo + ((size_t)b * KLEN + k0) * 1024 + c0;
    int t = threadIdx.x;
    int rr = t >> 4, cc4 = (t & 15) * 4;
#pragma unroll
    for (int it = 0; it < 4; ++it) {
        int r = rr + it * 16;
        float4 v = *(const float4*)(src + (size_t)r * DIMM + cc4);
        float f[4] = {v.x, v.y, v.z, v.w};
        ushort4v hi, lo;
#pragma unroll
        for (int e = 0; e < 4; ++e) {
            unsigned short h = f2bf(f[e]);
            hi[e] = h;
            lo[e] = f2bf(f[e] - bf2f(h));
            tile[r][cc4 + e] = h;
        }
        *(ushort4v*)(hl + (size_t)r * 1024 + cc4) = hi;
        *(ushort4v*)(hl + (size_t)r * 1024 + 512 + cc4) = lo;
    }
    __syncthreads();
#pragma unroll
    for (int it = 0; it < 2; ++it) {
        int u = t + it * 256;
        int c = u >> 3;                                // 0..63 (dim within tile)
        int kk = (u & 7) * 8;                          // 16B chunk along k
        ushort8v o;
#pragma unroll
        for (int e = 0; e < 8; ++e) o[e] = tile[kk + e][c];
        *(ushort8v*)(ctxT + ((size_t)b * DIMM + c0 + c) * KLEN + k0 + kk) = o;
    }
}

// ---------- softmax over rows of 4096: fp32 in-place + bf16 copy ----------
__global__ __launch_bounds__(256) void softmax_k(float* __restrict__ S,
                                                 unsigned short* __restrict__ Pb) {
    size_t row = blockIdx.x;
    float* p = S + row * KLEN;
    int t = threadIdx.x;
    int lane = t & 63, wv = t >> 6;
    float4 v[4];
    float mx = -3.0e38f;
#pragma unroll
    for (int i = 0; i < 4; ++i) {
        v[i] = *(const float4*)(p + i * 1024 + t * 4);
        mx = fmaxf(mx, fmaxf(fmaxf(v[i].x, v[i].y), fmaxf(v[i].z, v[i].w)));
    }
#pragma unroll
    for (int m = 32; m >= 1; m >>= 1) mx = fmaxf(mx, __shfl_xor(mx, m, 64));
    __shared__ float redm[4], reds[4];
    if (lane == 0) redm[wv] = mx;
    __syncthreads();
    mx = fmaxf(fmaxf(redm[0], redm[1]), fmaxf(redm[2], redm[3]));
    float sum = 0.f;
#pragma unroll
    for (int i = 0; i < 4; ++i) {
        v[i].x = __expf(v[i].x - mx); v[i].y = __expf(v[i].y - mx);
        v[i].z = __expf(v[i].z - mx); v[i].w = __expf(v[i].w - mx);
        sum += v[i].x + v[i].y + v[i].z + v[i].w;
    }
#pragma unroll
    for (int m = 32; m >= 1; m >>= 1) sum += __shfl_xor(sum, m, 64);
    if (lane == 0) reds[wv] = sum;
    __syncthreads();
    float inv = 1.0f / (reds[0] + reds[1] + reds[2] + reds[3]);
    unsigned short* pb = Pb + row * KLEN;
#pragma unroll
    for (int i = 0; i < 4; ++i) {
        float4 w;
        w.x = v[i].x * inv; w.y = v[i].y * inv; w.z = v[i].z * inv; w.w = v[i].w * inv;
        *(float4*)(p + i * 1024 + t * 4) = w;
        ushort4v h;
        h[0] = f2bf(w.x); h[1] = f2bf(w.y); h[2] = f2bf(w.z); h[3] = f2bf(w.w);
        *(ushort4v*)(pb + i * 1024 + t * 4) = h;
    }
}

// ---------- generic C = A * B^T GEMM (both operands K-major bf16), fp32 acc ----------
// BM x BN tile, BK=64, 4 waves (2 wm x 2 wn); wave = (BM/32) x (BN/32) frags of
// 16x16x32 MFMA. QK uses BM=128/BN=128 (frozen plateau: 107 us / 963 TF; r1/r2/
// r4/r6 structure experiments all regressed).
// R8 (this round): PV/out move to BM=64/BN=64. Rationale: their grids (512 blocks)
//   gave only 2 blk/CU; the 2-barrier loop hides its staging/barrier drain purely
//   via cross-block wave overlap (r2: 2 blk/CU -> MfmaUtil 33%; r5: split-K's
//   gross occupancy gain ~= its comb_k+partials overhead). BM=64 doubles the grid
//   to 1024 = 4 blk/CU with ZERO overhead. Staging ratio worsens 25% (32 MFMA per
//   16 KB vs 64 per 24 KB); bet: occupancy > staging ratio, worth ~10-15 us.
//   Accumulation order per output element unchanged -> absmax must stay bit-equal.
// SWZ (PV/out): z-chunked bijective remap -> XCD n owns batch n (nblk%8==0).
// EPI: 0 = store fp32; 1 = store bf16; 2 = tanh(x + bias[col]) fp32
// REMAP (QK split-bf16, virtual K=1536): A=[Al|Ah], B=[Bh|Bl], 3 panels.
template <int EPI, bool REMAP, int BM, int BN, bool SWZ>
__global__ __launch_bounds__(256, 4) void gemm_bt(
    const unsigned short* __restrict__ A,
    const unsigned short* __restrict__ Bm,
    float* __restrict__ Cf, unsigned short* __restrict__ Cb,
    const float* __restrict__ bias,
    int Ktiles, long lda, long ldb, long ldc,
    long a_bs, long b_bs, long c_bs) {
    constexpr int MI = BM / 32;                        // A frags per wave (4 or 2)
    constexpr int NF = BN / 32;                        // B frags per wave (4 or 2)
    __shared__ unsigned short sA[BM * 64];
    __shared__ unsigned short sB[BN * 64];

    int bx, by, bz;
    if constexpr (SWZ) {
        int nx = gridDim.x, ny = gridDim.y;
        int nblk = nx * ny * (int)gridDim.z;
        int id = (int)blockIdx.x + nx * ((int)blockIdx.y + ny * (int)blockIdx.z);
        int wid = (id & 7) * (nblk >> 3) + (id >> 3);
        bx = wid % nx;
        int rem = wid / nx;
        by = rem % ny;
        bz = rem / ny;
    } else {
        bx = blockIdx.x; by = blockIdx.y; bz = blockIdx.z;
    }

    const int tid = threadIdx.x;
    const int lane = tid & 63;
    const int wv = tid >> 6;
    const int wm = wv >> 1, wn = wv & 1;
    const int mlane = lane & 15, quad = lane >> 4;
    const unsigned short* Ab = A + (size_t)bz * a_bs + (size_t)by * BM * lda;
    const unsigned short* Bb = Bm + (size_t)bz * b_bs + (size_t)bx * BN * ldb;
    const int r8 = tid >> 3;
    const int c8 = (tid & 7) << 3;
    const int cg = ((tid & 7) ^ ((tid >> 3) & 7)) << 3;
    unsigned short* la = sA + r8 * 64 + c8;
    unsigned short* lb = sB + r8 * 64 + c8;

    floatx4 acc[MI][NF] = {};

    for (int kt = 0; kt < Ktiles; ++kt) {
        long kv = (long)kt * 64;
        long ka = kv, kb = kv;
        if (REMAP) {
            ka = kv < 512 ? kv + 512 : (kv < 1024 ? kv : kv - 1024);
            kb = kv < 1024 ? kv : kv - 1024;
        }
        if (kt) __syncthreads();                       // protect LDS from overwrite
        const unsigned short* ga = Ab + (size_t)r8 * lda + ka + cg;
        const unsigned short* gb = Bb + (size_t)r8 * ldb + kb + cg;
#pragma unroll
        for (int it = 0; it < BM / 32; ++it)
            gload16(ga + (size_t)(it * 32) * lda, la + it * 2048);
#pragma unroll
        for (int it = 0; it < BN / 32; ++it)
            gload16(gb + (size_t)(it * 32) * ldb, lb + it * 2048);
        __syncthreads();                               // drains vmcnt before barrier
#pragma unroll
        for (int s = 0; s < 2; ++s) {
            const int swz = (((s * 4 + quad) ^ (mlane & 7)) << 3);
            short8 af[MI];
#pragma unroll
            for (int i = 0; i < MI; ++i)
                af[i] = *(const short8*)(sA + (wm * (BM / 2) + i * 16 + mlane) * 64 + swz);
#pragma unroll
            for (int j = 0; j < NF; ++j) {             // stream bf: keeps live regs low
                short8 bfj = *(const short8*)(sB + (wn * (BN / 2) + j * 16 + mlane) * 64 + swz);
#pragma unroll
                for (int i = 0; i < MI; ++i)
                    acc[i][j] = __builtin_amdgcn_mfma_f32_16x16x32_bf16(af[i], bfj, acc[i][j], 0, 0, 0);
            }
        }
    }

    // epilogue: C/D layout col=lane&15, row=quad*4+reg
    size_t crow0 = (size_t)by * BM + wm * (BM / 2) + quad * 4;
    size_t ccol0 = (size_t)bx * BN + wn * (BN / 2) + mlane;
    size_t cbase = (size_t)bz * c_bs;
#pragma unroll
    for (int i = 0; i < MI; ++i) {
#pragma unroll
        for (int j = 0; j < NF; ++j) {
            size_t gr = crow0 + i * 16;
            size_t gc = ccol0 + j * 16;
#pragma unroll
            for (int r = 0; r < 4; ++r) {
                float vv = acc[i][j][r];
                size_t off = cbase + (gr + r) * ldc + gc;
                if (EPI == 0) Cf[off] = vv;
                else if (EPI == 1) Cb[off] = f2bf(vv);
                else Cf[off] = fast_tanh(vv + bias[gc]);
            }
        }
    }
}

extern "C" void kernel_launch(void* const* d_in, const int* in_sizes, int n_in,
                              void* d_out, int out_size, void* d_ws, size_t ws_size,
                              hipStream_t stream) {
    (void)in_sizes; (void)n_in; (void)out_size; (void)ws_size;
    const float* outp = (const float*)d_in[0];   // [8,1024,512]
    const float* ctx  = (const float*)d_in[1];   // [8,4096,512]
    const float* W    = (const float*)d_in[2];   // [512,1024]  (already K-major for C=A*W^T)
    const float* bias = (const float*)d_in[3];   // [512]

    float* out0 = (float*)d_out;                              // [8,1024,512]
    float* attn = out0 + (size_t)NB * QLEN * DIMM;            // [8,1024,4096]

    unsigned char* w = (unsigned char*)d_ws;
    // Region plan (113 MiB peak, time-aliased):
    //   R1 (16 MiB): A2 = [outLo|outHi]          -> later: combined [mix | outHi]
    //   R2 (64 MiB): B2 = [ctxHi|ctxLo]          -> later: attn bf16
    //   R3 (32 MiB): ctxT hi bf16 [b,512,4096]
    //   R4 ( 1 MiB): W bf16
    unsigned short* R1 = (unsigned short*)(w);
    unsigned short* R2 = (unsigned short*)(w + (16ull << 20));
    unsigned short* R3 = (unsigned short*)(w + (80ull << 20));
    unsigned short* R4 = (unsigned short*)(w + (112ull << 20));

    // 1. prep (output split + W convert fused into one dispatch; ctx read once)
    prep_qw<<<4608, 256, 0, stream>>>(outp, W, R1, R4);
    prep_ctx<<<dim3(8, 64, 8), 256, 0, stream>>>(ctx, R2, R3);       // ctx -> B2 + ctxT

    // 2. QK^T split-bf16 (virtual K=1536) -> raw logits (frozen 2-barrier kernel,
    //    2 z-split dispatches; r7 measured this config = session best).
    for (int h = 0; h < 2; ++h) {
        gemm_bt<0, true, 128, 128, false><<<dim3(32, 8, 4), 256, 0, stream>>>(
            R1 + (size_t)h * 4 * QLEN * 1024,
            R2 + (size_t)h * 4 * KLEN * 1024,
            attn + (size_t)h * 4 * QLEN * KLEN, nullptr, nullptr,
            24, 1024, 1024, 4096,
            (long)QLEN * 1024, (long)KLEN * 1024, (long)QLEN * KLEN);
    }

    // 3. softmax rows: fp32 in-place + bf16 copy into R2 (B2 is dead)
    softmax_k<<<8192, 256, 0, stream>>>(attn, R2);

    // 4. PV: mix = attn_bf16 * ctxT^T -> combined[:,0:512] (bf16, overwrites dead outLo)
    //    BM=64: grid (8,16,8) = 1024 blocks = 4 blk/CU (occupancy fix, zero overhead)
    gemm_bt<1, false, 64, 64, true><<<dim3(8, 16, 8), 256, 0, stream>>>(
        R2, R3, nullptr, R1, nullptr,
        64, 4096, 4096, 1024,
        (long)QLEN * KLEN, (long)DIMM * KLEN, (long)QLEN * 1024);

    // 5. out = tanh(combined * W^T + b); BM=64: grid (8,128) = 1024 blocks = 4 blk/CU
    gemm_bt<2, false, 64, 64, true><<<dim3(8, 128, 1), 256, 0, stream>>>(
        R1, R4, out0, nullptr, bias,
        16, 1024, 1024, 512, 0, 0, 0);
}